// Round 7
// baseline (187.623 us; speedup 1.0000x reference)
//
#include <hip/hip_runtime.h>
#include <hip/hip_bf16.h>
#include <math.h>

#define HH 80
#define WW 80
#define NPIX 6400
#define LL 21
#define NITER 5
#define C_LOG2E 1.44269504088896f
#define RAD 16              // gaussian truncation radius: dropped mass <= 1.2e-7

// bilateral MFMA kernel geometry (proven: SJ=320, 4 blocks/CU, 1000 blocks)
#define SJ  320             // j-slice per block
#define CHK (SJ / 32)       // 10 chunks of 32 j
#define QROW 164            // Q LDS row stride in u32 (41 16B-units)
#define QROWS 22            // rows 0..20 labels, 21 = ones; lanes m>=22 alias row 0
#define NBLK 1000           // 50 x 20 tiles == one co-residency round at 4/CU
#define NBY  20             // j0 slices (partial-accumulator count)
#define NLP  11             // packed row-pairs (22 rows -> 11 u32 rows)
#define SPWORK (LL * NPIX)  // 134400 spat_x pixel-rows, uniform over blocks

// merged spat_y+reduce+combine kernel geometry (R1-proven: 200 x 1024)
#define PXB 32              // pixels per block
#define SYB (NPIX / PXB)    // 200 blocks
#define SYT 1024            // A1 672 tasks + A2 352 tasks = 1024 exact

typedef short short8 __attribute__((ext_vector_type(8)));
typedef float f32x16 __attribute__((ext_vector_type(16)));

__device__ inline ushort bf_rne(float x) {
    uint u = __float_as_uint(x);
    return (ushort)((u + 0x7FFFu + ((u >> 16) & 1u)) >> 16);
}
__device__ inline float bf_to_f(ushort h) { return __uint_as_float(((uint)h) << 16); }
__device__ inline uint pk2(float a, float b) {
    __hip_bfloat162 t = __float22bfloat162_rn(make_float2(a, b));
    return *reinterpret_cast<uint*>(&t);
}
// 1-op RTZ pack for E (per-j error cancels in the bi/norm ratio)
__device__ inline uint pk2z(float a, float b) {
    return __builtin_amdgcn_perm(__float_as_uint(b), __float_as_uint(a), 0x07060302u);
}
__device__ inline float fexp2(float x) { return __builtin_amdgcn_exp2f(x); }

// ================ setup: blocks 0..49 = pre+softmax0 (128 px each), block 50 = mats
__global__ void k_setup(const float* __restrict__ img, const float* __restrict__ unary,
                        const float* __restrict__ Wsp, const float* __restrict__ Wbi,
                        const float* __restrict__ C, ushort* __restrict__ fjg,
                        uint* __restrict__ fig, float* __restrict__ mhs2,
                        float* __restrict__ nsp, ushort* __restrict__ qb16,
                        float* __restrict__ M1, float* __restrict__ M2) {
    int tid = threadIdx.x;
    if (blockIdx.x == 50) {           // ---- mats role
        for (int t = tid; t < LL * LL; t += 256) {
            int l = t / LL, k = t % LL;
            float a = 0.f, b = 0.f;
            for (int m = 0; m < LL; m++) {
                a += C[l * LL + m] * Wsp[m * LL + k];
                b += C[l * LL + m] * Wbi[m * LL + k];
            }
            M1[t] = a; M2[t] = b;
        }
        return;
    }
    __shared__ float sxT[WW];
    if (tid < WW) {       // FULL-sum normalizer (reference-exact)
        float s = 0.f;
        for (int t = 0; t < WW; t++) { float d = (float)(tid - t); s += __expf(-d * d * (1.0f / 18.0f)); }
        sxT[tid] = s;
    }
    __syncthreads();
    if (tid >= 128) return;
    int i = blockIdx.x * 128 + tid;
    int x = i % WW, y = i / WW;
    float f[5];
    f[0] = (float)x * (1.0f / 160.0f);
    f[1] = (float)y * (1.0f / 160.0f);
    f[2] = (img[0 * NPIX + i] - 127.5f) * (1.0f / 3.0f);
    f[3] = (img[1 * NPIX + i] - 127.5f) * (1.0f / 3.0f);
    f[4] = (img[2 * NPIX + i] - 127.5f) * (1.0f / 3.0f);
    float s = 0.f;
    ushort hi[5], lo[5], Hi[5], Lo[5];
#pragma unroll
    for (int c = 0; c < 5; c++) {
        s += f[c] * f[c];
        hi[c] = bf_rne(f[c]);
        lo[c] = bf_rne(f[c] - bf_to_f(hi[c]));
        float a = C_LOG2E * f[c];
        Hi[c] = bf_rne(a);
        Lo[c] = bf_rne(a - bf_to_f(Hi[c]));
    }
    float mi = -0.5f * C_LOG2E * s;
    // mhs2: per-32-chunk [h][16] permuted layout so k_iter1 loads its MFMA
    // C-operand as 4x dwordx4 (pos: swap bit3<->bit4 of i&31)
    {
        int r = i & 31;
        int pos = (r & 7) | ((r & 8) << 1) | ((r & 16) >> 1);
        mhs2[(size_t)(i >> 5) * 32 + pos] = mi;
    }
    ushort mih = bf_rne(mi);
    ushort mil = bf_rne(mi - bf_to_f(mih));
    {   // A-side row: [h0..h4, l2,l3,l4, h2,h3,h4, l2,l3,l4, 1.0, 1.0]
        ushort r0[16] = { hi[0], hi[1], hi[2], hi[3], hi[4], lo[2], lo[3], lo[4],
                          hi[2], hi[3], hi[4], lo[2], lo[3], lo[4], 0x3F80, 0x3F80 };
        uint4 w0, w1;
        w0.x = (uint)r0[0] | ((uint)r0[1] << 16);  w0.y = (uint)r0[2] | ((uint)r0[3] << 16);
        w0.z = (uint)r0[4] | ((uint)r0[5] << 16);  w0.w = (uint)r0[6] | ((uint)r0[7] << 16);
        w1.x = (uint)r0[8] | ((uint)r0[9] << 16);  w1.y = (uint)r0[10] | ((uint)r0[11] << 16);
        w1.z = (uint)r0[12] | ((uint)r0[13] << 16); w1.w = (uint)r0[14] | ((uint)r0[15] << 16);
        *(uint4*)(fjg + (size_t)i * 16) = w0;
        *(uint4*)(fjg + (size_t)i * 16 + 8) = w1;
    }
    {   // B-side row: [H0..H4, H2,H3,H4, L2,L3,L4, L2,L3,L4, mih, mil]
        ushort r1[16] = { Hi[0], Hi[1], Hi[2], Hi[3], Hi[4], Hi[2], Hi[3], Hi[4],
                          Lo[2], Lo[3], Lo[4], Lo[2], Lo[3], Lo[4], mih, mil };
        uint4 w0, w1;
        w0.x = (uint)r1[0] | ((uint)r1[1] << 16);  w0.y = (uint)r1[2] | ((uint)r1[3] << 16);
        w0.z = (uint)r1[4] | ((uint)r1[5] << 16);  w0.w = (uint)r1[6] | ((uint)r1[7] << 16);
        w1.x = (uint)r1[8] | ((uint)r1[9] << 16);  w1.y = (uint)r1[10] | ((uint)r1[11] << 16);
        w1.z = (uint)r1[12] | ((uint)r1[13] << 16); w1.w = (uint)r1[14] | ((uint)r1[15] << 16);
        *(uint4*)(fig + (size_t)i * 8) = w0;
        *(uint4*)(fig + (size_t)i * 8 + 4) = w1;
    }
    nsp[i] = 1.0f / (sxT[x] * sxT[y] + 1e-8f);
    float v[LL];
    float mx = -1e30f;
    for (int l = 0; l < LL; l++) { v[l] = unary[l * NPIX + i]; mx = fmaxf(mx, v[l]); }
    float ss = 0.f;
    for (int l = 0; l < LL; l++) { v[l] = __expf(v[l] - mx); ss += v[l]; }
    float r = 1.0f / ss;
    for (int l = 0; l < LL; l++) qb16[(size_t)l * NPIX + i] = bf_rne(v[l] * r);
}

// ================ iteration kernel 1: 1000 blocks, one co-residency round.
// bilat MFMA tile; bip partials packed bf16x2 (rows l,l+1 per u32, 11 rows).
// LDS: only Q and Fj (XOR-swizzled 16B units, (row>>3)&1 -> max 2-way = free).
// mhs C-operand comes from global mhs2 via dwordx4 (VMEM pipe is idle in-loop).
// Uniform ~134-px spat_x rider (reads qb16), radius-16 truncated taps.
__global__ __launch_bounds__(256, 4)
void k_iter1(const float* __restrict__ mhs2, const ushort* __restrict__ fjg,
             const uint* __restrict__ fig, const ushort* __restrict__ qb16,
             uint* __restrict__ bip, float* __restrict__ tmpx) {
    __shared__ __align__(16) uint  FjL[SJ * 12];
    __shared__ __align__(16) uint  QL[QROWS * QROW];
    __shared__ float gT[WW];
    int tid = threadIdx.x;
    int bid = blockIdx.x;
    int bx = bid % 50, by = bid / 50;
    int j0 = by * SJ;
    // ---- stage Q first (most global-load latency to hide); uint4 vectorized,
    // 16B-unit XOR swizzle by (l>>3)&1 breaks the dRow=8 4-way bank conflict.
    for (int idx = tid; idx < QROWS * 40; idx += 256) {
        int l = idx / 40, u = idx - l * 40;
        uint4 v;
        if (l < LL) {
            v = *((const uint4*)(qb16 + ((size_t)l * NPIX + j0)) + u);
        } else {
            v.x = 0x3F803F80u; v.y = 0x3F803F80u; v.z = 0x3F803F80u; v.w = 0x3F803F80u;
        }
        *(uint4*)&QL[l * QROW + ((u ^ ((l >> 3) & 1)) << 2)] = v;
    }
    // Fj rows, same swizzle on the two 16B halves by (r>>3)&1
    for (int idx = tid; idx < SJ * 2; idx += 256) {
        int r = idx >> 1, hf = idx & 1;
        uint4 v = ((const uint4*)(fjg + (size_t)(j0 + r) * 16))[hf];
        *(uint4*)&FjL[r * 12 + ((hf ^ ((r >> 3) & 1)) << 2)] = v;
    }
    if (tid < WW) gT[tid] = __expf(-(float)(tid * tid) * (1.0f / 18.0f));
    int lane = tid & 63, wid = tid >> 6;
    int h = lane >> 5, m = lane & 31;
    int i = bx * 128 + wid * 32 + m;
    union U8 { uint u[4]; short8 s; };
    U8 bfr;
    {
        uint4 bv = *(const uint4*)(fig + (size_t)i * 8 + h * 4);
        bfr.u[0] = bv.x; bfr.u[1] = bv.y; bfr.u[2] = bv.z; bfr.u[3] = bv.w;
    }
    int jrow = (m & ~12) | ((m & 4) << 1) | ((m & 8) >> 1);
    int xf = (jrow >> 3) & 1;
    int qrow = (m < QROWS) ? m : 0;
    int xq = (qrow >> 3) & 1;
    const uint* qlbase = &QL[qrow * QROW];
    const float4* mbase = (const float4*)(mhs2 + (size_t)(j0 >> 5) * 32) + h * 4;
    __syncthreads();
    f32x16 acc;
#pragma unroll
    for (int k = 0; k < 16; k++) acc[k] = 0.f;
    for (int c = 0; c < CHK; c++) {
        int jb = c * 32;
        f32x16 cv;
        {
            const float4* mc = mbase + c * 8;
            float4 a0 = mc[0], a1 = mc[1], a2 = mc[2], a3 = mc[3];
            cv[0] = a0.x;  cv[1] = a0.y;  cv[2] = a0.z;  cv[3] = a0.w;
            cv[4] = a1.x;  cv[5] = a1.y;  cv[6] = a1.z;  cv[7] = a1.w;
            cv[8] = a2.x;  cv[9] = a2.y;  cv[10] = a2.z; cv[11] = a2.w;
            cv[12] = a3.x; cv[13] = a3.y; cv[14] = a3.z; cv[15] = a3.w;
        }
        short8 af = *(const short8*)&FjL[(jb + jrow) * 12 + ((h ^ xf) << 2)];
        f32x16 d1 = __builtin_amdgcn_mfma_f32_32x32x16_bf16(af, bfr.s, cv, 0, 0, 0);
        short8 qa = *(const short8*)(qlbase + (((c * 4 + h) ^ xq) << 2));
        short8 qb = *(const short8*)(qlbase + (((c * 4 + 2 + h) ^ xq) << 2));
        U8 ea;
        ea.u[0] = pk2z(fexp2(d1[0]), fexp2(d1[1]));
        ea.u[1] = pk2z(fexp2(d1[2]), fexp2(d1[3]));
        ea.u[2] = pk2z(fexp2(d1[4]), fexp2(d1[5]));
        ea.u[3] = pk2z(fexp2(d1[6]), fexp2(d1[7]));
        acc = __builtin_amdgcn_mfma_f32_32x32x16_bf16(qa, ea.s, acc, 0, 0, 0);
        U8 eb;
        eb.u[0] = pk2z(fexp2(d1[8]),  fexp2(d1[9]));
        eb.u[1] = pk2z(fexp2(d1[10]), fexp2(d1[11]));
        eb.u[2] = pk2z(fexp2(d1[12]), fexp2(d1[13]));
        eb.u[3] = pk2z(fexp2(d1[14]), fexp2(d1[15]));
        acc = __builtin_amdgcn_mfma_f32_32x32x16_bf16(qb, eb.s, acc, 0, 0, 0);
    }
    // ---- epilogue: pack adjacent-l pairs (C-layout gives l, l+1 at regs r, r+1
    // for even r) into bf16x2; rows 0..21 -> row-pairs 0..10, skip l >= 22.
#pragma unroll
    for (int r = 0; r < 16; r += 2) {
        int l = (r & 3) + 8 * (r >> 2) + 4 * h;    // even l of the pair
        if (l < LL + 1)
            bip[((size_t)by * NLP + (l >> 1)) * NPIX + i] = pk2(acc[r], acc[r + 1]);
    }
    // ---- spat_x rider: uniform ~134-px slice; reads bf16 Q; radius-16 taps
    {
        int start = (int)(((long)bid * SPWORK) / NBLK);
        int end   = (int)(((long)(bid + 1) * SPWORK) / NBLK);
        int cnt = end - start;
        if (tid < cnt) {
            int fidx = start + tid;
            int l = fidx / NPIX;
            int p = fidx - l * NPIX;
            int x = p % WW, y = p / WW;
            const ushort* rowq = qb16 + (size_t)l * NPIX + y * WW;
            int xlo = x - RAD; if (xlo < 0) xlo = 0;
            int xhi = x + RAD; if (xhi > WW - 1) xhi = WW - 1;
            float s = 0.f;
            for (int xp = xlo; xp <= xhi; xp++) {
                int d = x - xp; d = d < 0 ? -d : d;
                s += gT[d] * bf_to_f(rowq[xp]);
            }
            tmpx[(size_t)l * NPIX + p] = s;
        }
    }
}

// ================ iteration kernel 2 (merged): spat_y + reduce + combine + softmax
// 200 blocks x 1024 thr (R1-proven); block owns ALL rows of its 32 pixels.
// Phase A1: 672 spat_y tasks (radius-16); Phase A2: 352 packed-reduce tasks
// on tid 672..1023 -- fully parallel, disjoint LDS.
__global__ __launch_bounds__(SYT)
void k_syc(const float* __restrict__ unary, const float* __restrict__ tmpx,
           const uint* __restrict__ bip, const float* __restrict__ nsp,
           const float* __restrict__ M1, const float* __restrict__ M2,
           ushort* __restrict__ qb16, float* __restrict__ out, int last) {
    __shared__ float m1s[LL * 24];
    __shared__ float m2s[LL * 24];
    __shared__ float gT[HH];
    __shared__ float svL[PXB][QROWS];   // [pxl][l] spatial (l<21)
    __shared__ float bvL[PXB][QROWS];   // [pxl][l] bilat reduce (l<=21)
    __shared__ float aex[PXB][QROWS];   // [pxl][l] combined logits
    int tid = threadIdx.x;
    int px0 = blockIdx.x * PXB;
    for (int t = tid; t < LL * LL; t += SYT) {
        int l = t / LL, k = t % LL;
        m1s[l * 24 + k] = M1[t];
        m2s[l * 24 + k] = M2[t];
    }
    if (tid < HH) gT[tid] = __expf(-(float)(tid * tid) * (1.0f / 18.0f));
    __syncthreads();
    // ---- phase A1: spat_y conv, 32 px x 21 labels = 672 tasks (tid < 672)
    if (tid < PXB * LL) {
        int pxl = tid & (PXB - 1);
        int l = tid / PXB;
        int px = px0 + pxl;
        int x = px % WW, y = px / WW;
        const float* base = tmpx + (size_t)l * NPIX + x;
        int ylo = y - RAD; if (ylo < 0) ylo = 0;
        int yhi = y + RAD; if (yhi > HH - 1) yhi = HH - 1;
        float s1 = 0.f;
        for (int yp = ylo; yp <= yhi; yp++) {
            int d = y - yp; d = d < 0 ? -d : d;
            s1 += gT[d] * base[yp * WW];
        }
        svL[pxl][l] = s1;
    } else {
        // ---- phase A2 (parallel with A1): packed bip reduce, 32 px x 11
        // row-pairs = 352 tasks on tid 672..1023
        int t2 = tid - PXB * LL;
        if (t2 < PXB * NLP) {
            int pxl = t2 & (PXB - 1);
            int lp = t2 / PXB;
            int px = px0 + pxl;
            float sa = 0.f, sb = 0.f;
            const uint* p = bip + (size_t)lp * NPIX + px;
#pragma unroll
            for (int byi = 0; byi < NBY; byi++) {
                uint v = p[(size_t)byi * NLP * NPIX];
                sa += __uint_as_float(v << 16);
                sb += __uint_as_float(v & 0xFFFF0000u);
            }
            bvL[pxl][2 * lp] = sa;
            bvL[pxl][2 * lp + 1] = sb;
        }
    }
    __syncthreads();
    // ---- phase B1: combine  a[l] = unary + ns*(M1.sv) + nb*(M2.bv)
    if (tid < PXB * LL) {
        int pxl = tid & (PXB - 1);
        int l = tid / PXB;            // 0..20
        int px = px0 + pxl;
        float ns = nsp[px];
        float nb = 1.0f / (bvL[pxl][LL] + 1e-8f);
        float s1 = 0.f, s2 = 0.f;
        const float* r1 = &m1s[l * 24];
        const float* r2 = &m2s[l * 24];
#pragma unroll
        for (int k = 0; k < LL; k++) {
            s1 = fmaf(r1[k], svL[pxl][k], s1);
            s2 = fmaf(r2[k], bvL[pxl][k], s2);
        }
        float a = unary[l * NPIX + px] + ns * s1 + nb * s2;
        if (last) out[(size_t)l * NPIX + px] = a;
        else      aex[pxl][l] = a;
    }
    if (last) return;
    __syncthreads();
    // ---- phase B2: per-pixel softmax -> qb16
    if (tid < PXB) {
        int px = px0 + tid;
        float mx = -1e30f;
        for (int l = 0; l < LL; l++) mx = fmaxf(mx, aex[tid][l]);
        float s = 0.f;
        float e[LL];
        for (int l = 0; l < LL; l++) { e[l] = __expf(aex[tid][l] - mx); s += e[l]; }
        float r = 1.0f / s;
        for (int l = 0; l < LL; l++)
            qb16[(size_t)l * NPIX + px] = bf_rne(e[l] * r);
    }
}

extern "C" void kernel_launch(void* const* d_in, const int* in_sizes, int n_in,
                              void* d_out, int out_size, void* d_ws, size_t ws_size,
                              hipStream_t stream) {
    const float* img   = (const float*)d_in[0];
    const float* unary = (const float*)d_in[1];
    const float* Wsp   = (const float*)d_in[2];
    const float* Wbi   = (const float*)d_in[3];
    const float* C     = (const float*)d_in[4];
    float* out = (float*)d_out;

    const int LN = LL * NPIX;
    float* w = (float*)d_ws;
    float*  tmpx = w;  w += LN;
    uint*   bip  = (uint*)w;    w += NBY * NLP * NPIX;  // packed bf16x2 partials
    float*  mhs2 = w;  w += NPIX;                      // permuted [chunk][h][16]
    float*  nsp  = w;  w += NPIX;
    ushort* fjg  = (ushort*)w;  w += 8 * NPIX;        // A-rows [N][16 bf16]
    uint*   fig  = (uint*)w;    w += 8 * NPIX;        // B-rows [N][8 u32]
    ushort* qb16 = (ushort*)w;  w += (LN + 1) / 2;    // Q in bf16 [21][N]
    float*  M1   = w;  w += LL * LL;
    float*  M2   = w;  w += LL * LL;

    k_setup<<<51, 256, 0, stream>>>(img, unary, Wsp, Wbi, C, fjg, fig, mhs2, nsp,
                                    qb16, M1, M2);
    for (int it = 0; it < NITER; it++) {
        int last = (it == NITER - 1);
        k_iter1<<<NBLK, 256, 0, stream>>>(mhs2, fjg, fig, qb16, bip, tmpx);
        k_syc<<<SYB, SYT, 0, stream>>>(unary, tmpx, bip, nsp, M1, M2, qb16, out, last);
    }
}

// Round 8
// 159.135 us; speedup vs baseline: 1.1790x; 1.1790x over previous
//
#include <hip/hip_runtime.h>
#include <hip/hip_bf16.h>
#include <math.h>

#define HH 80
#define WW 80
#define NPIX 6400
#define LL 21
#define NITER 5
#define C_LOG2E 1.44269504088896f
#define RAD 16              // truncation radius; dropped tap weight <= 1.1e-7
#define W33 (2 * RAD + 1)   // fixed trip count -> compiler fully unrolls

// bilateral MFMA kernel geometry (proven: SJ=320, 4 blocks/CU, 1000 blocks)
#define SJ  320             // j-slice per block
#define CHK (SJ / 32)       // 10 chunks of 32 j
#define QROW 164            // Q LDS row stride in u32 (41 16B-units)
#define QROWS 22            // rows 0..20 labels, 21 = ones; lanes m>=22 alias row 0
#define NBLK 1000           // 50 x 20 tiles == one co-residency round at 4/CU
#define NBY  20             // j0 slices (partial-accumulator count)
#define NLP  11             // packed row-pairs (22 rows -> 11 u32 rows)
#define SPWORK (LL * NPIX)  // 134400 spat_x pixel-rows, uniform over blocks

// merged spat_y+reduce+combine kernel geometry (R1-proven: 200 x 1024)
#define PXB 32              // pixels per block
#define SYB (NPIX / PXB)    // 200 blocks
#define SYT 1024            // A1 672 tasks + A2 352 tasks

typedef short short8 __attribute__((ext_vector_type(8)));
typedef float f32x16 __attribute__((ext_vector_type(16)));

__device__ inline ushort bf_rne(float x) {
    uint u = __float_as_uint(x);
    return (ushort)((u + 0x7FFFu + ((u >> 16) & 1u)) >> 16);
}
__device__ inline float bf_to_f(ushort h) { return __uint_as_float(((uint)h) << 16); }
__device__ inline uint pk2(float a, float b) {
    __hip_bfloat162 t = __float22bfloat162_rn(make_float2(a, b));
    return *reinterpret_cast<uint*>(&t);
}
// 1-op RTZ pack for E (per-j error cancels in the bi/norm ratio)
__device__ inline uint pk2z(float a, float b) {
    return __builtin_amdgcn_perm(__float_as_uint(b), __float_as_uint(a), 0x07060302u);
}
__device__ inline float fexp2(float x) { return __builtin_amdgcn_exp2f(x); }

// ================ setup: blocks 0..49 = pre+softmax0 (128 px each), block 50 = mats
__global__ void k_setup(const float* __restrict__ img, const float* __restrict__ unary,
                        const float* __restrict__ Wsp, const float* __restrict__ Wbi,
                        const float* __restrict__ C, ushort* __restrict__ fjg,
                        uint* __restrict__ fig, float* __restrict__ mhs2,
                        float* __restrict__ nsp, ushort* __restrict__ qb16,
                        float* __restrict__ M1, float* __restrict__ M2) {
    int tid = threadIdx.x;
    if (blockIdx.x == 50) {           // ---- mats role
        for (int t = tid; t < LL * LL; t += 256) {
            int l = t / LL, k = t % LL;
            float a = 0.f, b = 0.f;
            for (int m = 0; m < LL; m++) {
                a += C[l * LL + m] * Wsp[m * LL + k];
                b += C[l * LL + m] * Wbi[m * LL + k];
            }
            M1[t] = a; M2[t] = b;
        }
        return;
    }
    __shared__ float sxT[WW];
    if (tid < WW) {       // FULL-sum normalizer (reference-exact)
        float s = 0.f;
        for (int t = 0; t < WW; t++) { float d = (float)(tid - t); s += __expf(-d * d * (1.0f / 18.0f)); }
        sxT[tid] = s;
    }
    __syncthreads();
    if (tid >= 128) return;
    int i = blockIdx.x * 128 + tid;
    int x = i % WW, y = i / WW;
    float f[5];
    f[0] = (float)x * (1.0f / 160.0f);
    f[1] = (float)y * (1.0f / 160.0f);
    f[2] = (img[0 * NPIX + i] - 127.5f) * (1.0f / 3.0f);
    f[3] = (img[1 * NPIX + i] - 127.5f) * (1.0f / 3.0f);
    f[4] = (img[2 * NPIX + i] - 127.5f) * (1.0f / 3.0f);
    float s = 0.f;
    ushort hi[5], lo[5], Hi[5], Lo[5];
#pragma unroll
    for (int c = 0; c < 5; c++) {
        s += f[c] * f[c];
        hi[c] = bf_rne(f[c]);
        lo[c] = bf_rne(f[c] - bf_to_f(hi[c]));
        float a = C_LOG2E * f[c];
        Hi[c] = bf_rne(a);
        Lo[c] = bf_rne(a - bf_to_f(Hi[c]));
    }
    float mi = -0.5f * C_LOG2E * s;
    // mhs2: per-32-chunk [h][16] permuted layout so k_iter1 loads its MFMA
    // C-operand as 4x dwordx4 (pos: swap bit3<->bit4 of i&31)
    {
        int r = i & 31;
        int pos = (r & 7) | ((r & 8) << 1) | ((r & 16) >> 1);
        mhs2[(size_t)(i >> 5) * 32 + pos] = mi;
    }
    ushort mih = bf_rne(mi);
    ushort mil = bf_rne(mi - bf_to_f(mih));
    {   // A-side row: [h0..h4, l2,l3,l4, h2,h3,h4, l2,l3,l4, 1.0, 1.0]
        ushort r0[16] = { hi[0], hi[1], hi[2], hi[3], hi[4], lo[2], lo[3], lo[4],
                          hi[2], hi[3], hi[4], lo[2], lo[3], lo[4], 0x3F80, 0x3F80 };
        uint4 w0, w1;
        w0.x = (uint)r0[0] | ((uint)r0[1] << 16);  w0.y = (uint)r0[2] | ((uint)r0[3] << 16);
        w0.z = (uint)r0[4] | ((uint)r0[5] << 16);  w0.w = (uint)r0[6] | ((uint)r0[7] << 16);
        w1.x = (uint)r0[8] | ((uint)r0[9] << 16);  w1.y = (uint)r0[10] | ((uint)r0[11] << 16);
        w1.z = (uint)r0[12] | ((uint)r0[13] << 16); w1.w = (uint)r0[14] | ((uint)r0[15] << 16);
        *(uint4*)(fjg + (size_t)i * 16) = w0;
        *(uint4*)(fjg + (size_t)i * 16 + 8) = w1;
    }
    {   // B-side row: [H0..H4, H2,H3,H4, L2,L3,L4, L2,L3,L4, mih, mil]
        ushort r1[16] = { Hi[0], Hi[1], Hi[2], Hi[3], Hi[4], Hi[2], Hi[3], Hi[4],
                          Lo[2], Lo[3], Lo[4], Lo[2], Lo[3], Lo[4], mih, mil };
        uint4 w0, w1;
        w0.x = (uint)r1[0] | ((uint)r1[1] << 16);  w0.y = (uint)r1[2] | ((uint)r1[3] << 16);
        w0.z = (uint)r1[4] | ((uint)r1[5] << 16);  w0.w = (uint)r1[6] | ((uint)r1[7] << 16);
        w1.x = (uint)r1[8] | ((uint)r1[9] << 16);  w1.y = (uint)r1[10] | ((uint)r1[11] << 16);
        w1.z = (uint)r1[12] | ((uint)r1[13] << 16); w1.w = (uint)r1[14] | ((uint)r1[15] << 16);
        *(uint4*)(fig + (size_t)i * 8) = w0;
        *(uint4*)(fig + (size_t)i * 8 + 4) = w1;
    }
    nsp[i] = 1.0f / (sxT[x] * sxT[y] + 1e-8f);
    float v[LL];
    float mx = -1e30f;
    for (int l = 0; l < LL; l++) { v[l] = unary[l * NPIX + i]; mx = fmaxf(mx, v[l]); }
    float ss = 0.f;
    for (int l = 0; l < LL; l++) { v[l] = __expf(v[l] - mx); ss += v[l]; }
    float r = 1.0f / ss;
    for (int l = 0; l < LL; l++) qb16[(size_t)l * NPIX + i] = bf_rne(v[l] * r);
}

// ================ iteration kernel 1: 1000 blocks, one co-residency round.
// bilat MFMA tile; bip partials packed bf16x2 (rows l,l+1 per u32, 11 rows).
// LDS: only Q and Fj (XOR-swizzled 16B units, (row>>3)&1 -> max 2-way = free).
// mhs C-operand comes from global mhs2 via dwordx4 (VMEM pipe is idle in-loop).
// Uniform ~134-px spat_x rider: FIXED-TRIP 33-tap window (clamped start) so
// the compiler fully unrolls and batches the loads (R7 lesson: runtime bounds
// rolled the loop and serialized on L2 latency).
__global__ __launch_bounds__(256, 4)
void k_iter1(const float* __restrict__ mhs2, const ushort* __restrict__ fjg,
             const uint* __restrict__ fig, const ushort* __restrict__ qb16,
             uint* __restrict__ bip, float* __restrict__ tmpx) {
    __shared__ __align__(16) uint  FjL[SJ * 12];
    __shared__ __align__(16) uint  QL[QROWS * QROW];
    __shared__ float gT[WW];
    int tid = threadIdx.x;
    int bid = blockIdx.x;
    int bx = bid % 50, by = bid / 50;
    int j0 = by * SJ;
    // ---- stage Q first (most global-load latency to hide); uint4 vectorized,
    // 16B-unit XOR swizzle by (l>>3)&1 breaks the dRow=8 4-way bank conflict.
    for (int idx = tid; idx < QROWS * 40; idx += 256) {
        int l = idx / 40, u = idx - l * 40;
        uint4 v;
        if (l < LL) {
            v = *((const uint4*)(qb16 + ((size_t)l * NPIX + j0)) + u);
        } else {
            v.x = 0x3F803F80u; v.y = 0x3F803F80u; v.z = 0x3F803F80u; v.w = 0x3F803F80u;
        }
        *(uint4*)&QL[l * QROW + ((u ^ ((l >> 3) & 1)) << 2)] = v;
    }
    // Fj rows, same swizzle on the two 16B halves by (r>>3)&1
    for (int idx = tid; idx < SJ * 2; idx += 256) {
        int r = idx >> 1, hf = idx & 1;
        uint4 v = ((const uint4*)(fjg + (size_t)(j0 + r) * 16))[hf];
        *(uint4*)&FjL[r * 12 + ((hf ^ ((r >> 3) & 1)) << 2)] = v;
    }
    if (tid < WW) gT[tid] = __expf(-(float)(tid * tid) * (1.0f / 18.0f));
    int lane = tid & 63, wid = tid >> 6;
    int h = lane >> 5, m = lane & 31;
    int i = bx * 128 + wid * 32 + m;
    union U8 { uint u[4]; short8 s; };
    U8 bfr;
    {
        uint4 bv = *(const uint4*)(fig + (size_t)i * 8 + h * 4);
        bfr.u[0] = bv.x; bfr.u[1] = bv.y; bfr.u[2] = bv.z; bfr.u[3] = bv.w;
    }
    int jrow = (m & ~12) | ((m & 4) << 1) | ((m & 8) >> 1);
    int xf = (jrow >> 3) & 1;
    int qrow = (m < QROWS) ? m : 0;
    int xq = (qrow >> 3) & 1;
    const uint* qlbase = &QL[qrow * QROW];
    const float4* mbase = (const float4*)(mhs2 + (size_t)(j0 >> 5) * 32) + h * 4;
    __syncthreads();
    f32x16 acc;
#pragma unroll
    for (int k = 0; k < 16; k++) acc[k] = 0.f;
    for (int c = 0; c < CHK; c++) {
        int jb = c * 32;
        f32x16 cv;
        {
            const float4* mc = mbase + c * 8;
            float4 a0 = mc[0], a1 = mc[1], a2 = mc[2], a3 = mc[3];
            cv[0] = a0.x;  cv[1] = a0.y;  cv[2] = a0.z;  cv[3] = a0.w;
            cv[4] = a1.x;  cv[5] = a1.y;  cv[6] = a1.z;  cv[7] = a1.w;
            cv[8] = a2.x;  cv[9] = a2.y;  cv[10] = a2.z; cv[11] = a2.w;
            cv[12] = a3.x; cv[13] = a3.y; cv[14] = a3.z; cv[15] = a3.w;
        }
        short8 af = *(const short8*)&FjL[(jb + jrow) * 12 + ((h ^ xf) << 2)];
        f32x16 d1 = __builtin_amdgcn_mfma_f32_32x32x16_bf16(af, bfr.s, cv, 0, 0, 0);
        short8 qa = *(const short8*)(qlbase + (((c * 4 + h) ^ xq) << 2));
        short8 qb = *(const short8*)(qlbase + (((c * 4 + 2 + h) ^ xq) << 2));
        U8 ea;
        ea.u[0] = pk2z(fexp2(d1[0]), fexp2(d1[1]));
        ea.u[1] = pk2z(fexp2(d1[2]), fexp2(d1[3]));
        ea.u[2] = pk2z(fexp2(d1[4]), fexp2(d1[5]));
        ea.u[3] = pk2z(fexp2(d1[6]), fexp2(d1[7]));
        acc = __builtin_amdgcn_mfma_f32_32x32x16_bf16(qa, ea.s, acc, 0, 0, 0);
        U8 eb;
        eb.u[0] = pk2z(fexp2(d1[8]),  fexp2(d1[9]));
        eb.u[1] = pk2z(fexp2(d1[10]), fexp2(d1[11]));
        eb.u[2] = pk2z(fexp2(d1[12]), fexp2(d1[13]));
        eb.u[3] = pk2z(fexp2(d1[14]), fexp2(d1[15]));
        acc = __builtin_amdgcn_mfma_f32_32x32x16_bf16(qb, eb.s, acc, 0, 0, 0);
    }
    // ---- epilogue: pack adjacent-l pairs (C-layout gives l, l+1 at regs r, r+1
    // for even r) into bf16x2; rows 0..21 -> row-pairs 0..10, skip l >= 22.
#pragma unroll
    for (int r = 0; r < 16; r += 2) {
        int l = (r & 3) + 8 * (r >> 2) + 4 * h;    // even l of the pair
        if (l < LL + 1)
            bip[((size_t)by * NLP + (l >> 1)) * NPIX + i] = pk2(acc[r], acc[r + 1]);
    }
    // ---- spat_x rider: uniform ~134-px slice; fixed-trip 33-tap window
    {
        int start = (int)(((long)bid * SPWORK) / NBLK);
        int end   = (int)(((long)(bid + 1) * SPWORK) / NBLK);
        int cnt = end - start;
        if (tid < cnt) {
            int fidx = start + tid;
            int l = fidx / NPIX;
            int p = fidx - l * NPIX;
            int x = p % WW, y = p / WW;
            int xlo = x - RAD;
            if (xlo < 0) xlo = 0;
            if (xlo > WW - W33) xlo = WW - W33;   // window always in-range
            const ushort* rw = qb16 + (size_t)l * NPIX + y * WW + xlo;
            float s = 0.f;
#pragma unroll
            for (int k = 0; k < W33; k++) {
                int d = x - xlo - k; d = d < 0 ? -d : d;   // 0..32
                s += gT[d] * bf_to_f(rw[k]);
            }
            tmpx[(size_t)l * NPIX + p] = s;
        }
    }
}

// ================ iteration kernel 2 (merged): spat_y + reduce + combine + softmax
// 200 blocks x 1024 thr (R1-proven); block owns ALL rows of its 32 pixels.
// Phase A1: 672 spat_y tasks, fixed-trip 33-tap window; Phase A2: 352
// packed-reduce tasks on tid 672..1023 -- fully parallel, disjoint LDS.
__global__ __launch_bounds__(SYT)
void k_syc(const float* __restrict__ unary, const float* __restrict__ tmpx,
           const uint* __restrict__ bip, const float* __restrict__ nsp,
           const float* __restrict__ M1, const float* __restrict__ M2,
           ushort* __restrict__ qb16, float* __restrict__ out, int last) {
    __shared__ float m1s[LL * 24];
    __shared__ float m2s[LL * 24];
    __shared__ float gT[HH];
    __shared__ float svL[PXB][QROWS];   // [pxl][l] spatial (l<21)
    __shared__ float bvL[PXB][QROWS];   // [pxl][l] bilat reduce (l<=21)
    __shared__ float aex[PXB][QROWS];   // [pxl][l] combined logits
    int tid = threadIdx.x;
    int px0 = blockIdx.x * PXB;
    for (int t = tid; t < LL * LL; t += SYT) {
        int l = t / LL, k = t % LL;
        m1s[l * 24 + k] = M1[t];
        m2s[l * 24 + k] = M2[t];
    }
    if (tid < HH) gT[tid] = __expf(-(float)(tid * tid) * (1.0f / 18.0f));
    __syncthreads();
    // ---- phase A1: spat_y conv, 32 px x 21 labels = 672 tasks (tid < 672)
    if (tid < PXB * LL) {
        int pxl = tid & (PXB - 1);
        int l = tid / PXB;
        int px = px0 + pxl;
        int x = px % WW, y = px / WW;
        int ylo = y - RAD;
        if (ylo < 0) ylo = 0;
        if (ylo > HH - W33) ylo = HH - W33;   // window always in-range
        const float* base = tmpx + (size_t)l * NPIX + ylo * WW + x;
        float s1 = 0.f;
#pragma unroll
        for (int k = 0; k < W33; k++) {
            int d = y - ylo - k; d = d < 0 ? -d : d;     // 0..32
            s1 += gT[d] * base[k * WW];
        }
        svL[pxl][l] = s1;
    } else {
        // ---- phase A2 (parallel with A1): packed bip reduce, 32 px x 11
        // row-pairs = 352 tasks on tid 672..1023
        int t2 = tid - PXB * LL;
        if (t2 < PXB * NLP) {
            int pxl = t2 & (PXB - 1);
            int lp = t2 / PXB;
            int px = px0 + pxl;
            float sa = 0.f, sb = 0.f;
            const uint* p = bip + (size_t)lp * NPIX + px;
#pragma unroll
            for (int byi = 0; byi < NBY; byi++) {
                uint v = p[(size_t)byi * NLP * NPIX];
                sa += __uint_as_float(v << 16);
                sb += __uint_as_float(v & 0xFFFF0000u);
            }
            bvL[pxl][2 * lp] = sa;
            bvL[pxl][2 * lp + 1] = sb;
        }
    }
    __syncthreads();
    // ---- phase B1: combine  a[l] = unary + ns*(M1.sv) + nb*(M2.bv)
    if (tid < PXB * LL) {
        int pxl = tid & (PXB - 1);
        int l = tid / PXB;            // 0..20
        int px = px0 + pxl;
        float ns = nsp[px];
        float nb = 1.0f / (bvL[pxl][LL] + 1e-8f);
        float s1 = 0.f, s2 = 0.f;
        const float* r1 = &m1s[l * 24];
        const float* r2 = &m2s[l * 24];
#pragma unroll
        for (int k = 0; k < LL; k++) {
            s1 = fmaf(r1[k], svL[pxl][k], s1);
            s2 = fmaf(r2[k], bvL[pxl][k], s2);
        }
        float a = unary[l * NPIX + px] + ns * s1 + nb * s2;
        if (last) out[(size_t)l * NPIX + px] = a;
        else      aex[pxl][l] = a;
    }
    if (last) return;
    __syncthreads();
    // ---- phase B2: per-pixel softmax -> qb16
    if (tid < PXB) {
        int px = px0 + tid;
        float mx = -1e30f;
        for (int l = 0; l < LL; l++) mx = fmaxf(mx, aex[tid][l]);
        float s = 0.f;
        float e[LL];
        for (int l = 0; l < LL; l++) { e[l] = __expf(aex[tid][l] - mx); s += e[l]; }
        float r = 1.0f / s;
        for (int l = 0; l < LL; l++)
            qb16[(size_t)l * NPIX + px] = bf_rne(e[l] * r);
    }
}

extern "C" void kernel_launch(void* const* d_in, const int* in_sizes, int n_in,
                              void* d_out, int out_size, void* d_ws, size_t ws_size,
                              hipStream_t stream) {
    const float* img   = (const float*)d_in[0];
    const float* unary = (const float*)d_in[1];
    const float* Wsp   = (const float*)d_in[2];
    const float* Wbi   = (const float*)d_in[3];
    const float* C     = (const float*)d_in[4];
    float* out = (float*)d_out;

    const int LN = LL * NPIX;
    float* w = (float*)d_ws;
    float*  tmpx = w;  w += LN;
    uint*   bip  = (uint*)w;    w += NBY * NLP * NPIX;  // packed bf16x2 partials
    float*  mhs2 = w;  w += NPIX;                      // permuted [chunk][h][16]
    float*  nsp  = w;  w += NPIX;
    ushort* fjg  = (ushort*)w;  w += 8 * NPIX;        // A-rows [N][16 bf16]
    uint*   fig  = (uint*)w;    w += 8 * NPIX;        // B-rows [N][8 u32]
    ushort* qb16 = (ushort*)w;  w += (LN + 1) / 2;    // Q in bf16 [21][N]
    float*  M1   = w;  w += LL * LL;
    float*  M2   = w;  w += LL * LL;

    k_setup<<<51, 256, 0, stream>>>(img, unary, Wsp, Wbi, C, fjg, fig, mhs2, nsp,
                                    qb16, M1, M2);
    for (int it = 0; it < NITER; it++) {
        int last = (it == NITER - 1);
        k_iter1<<<NBLK, 256, 0, stream>>>(mhs2, fjg, fig, qb16, bip, tmpx);
        k_syc<<<SYB, SYT, 0, stream>>>(unary, tmpx, bip, nsp, M1, M2, qb16, out, last);
    }
}